// Round 1
// baseline (2614.822 us; speedup 1.0000x reference)
//
#include <hip/hip_runtime.h>

#define D_FEAT 128

// COO SpMM baseline: one wave (64 lanes) per edge, each lane owns 2 features.
// out[row[e], :] += vals[e] * embeds[col[e], :]  via f32 atomics (device-scope).
__global__ void __launch_bounds__(256) spmm_atomic_kernel(
    const int* __restrict__ row,
    const int* __restrict__ col,
    const float* __restrict__ vals,
    const float* __restrict__ embeds,
    float* __restrict__ out,
    int n_edges)
{
    const int lane = threadIdx.x & 63;
    const int wave_in_block = threadIdx.x >> 6;
    const int waves_per_block = blockDim.x >> 6;
    const int n_waves = gridDim.x * waves_per_block;
    int wave_id = blockIdx.x * waves_per_block + wave_in_block;

    for (int e = wave_id; e < n_edges; e += n_waves) {
        const int r = row[e];           // wave-uniform
        const int c = col[e];           // wave-uniform
        const float v = vals[e];        // wave-uniform

        // coalesced 512B gather: lanes 0..63 cover 128 contiguous floats
        const float2 emb =
            *reinterpret_cast<const float2*>(&embeds[(size_t)c * D_FEAT + lane * 2]);

        float* o = &out[(size_t)r * D_FEAT + lane * 2];
        atomicAdd(o,     emb.x * v);
        atomicAdd(o + 1, emb.y * v);
    }
}

extern "C" void kernel_launch(void* const* d_in, const int* in_sizes, int n_in,
                              void* d_out, int out_size, void* d_ws, size_t ws_size,
                              hipStream_t stream) {
    const int*   row    = (const int*)d_in[0];
    const int*   col    = (const int*)d_in[1];
    const float* vals   = (const float*)d_in[2];
    const float* embeds = (const float*)d_in[3];
    float*       out    = (float*)d_out;

    const int n_edges = in_sizes[0];

    // Output must be zeroed every call (harness poisons once, never re-poisons).
    hipMemsetAsync(d_out, 0, (size_t)out_size * sizeof(float), stream);

    // 2048 blocks x 256 threads = 8192 waves; grid-stride over edges.
    const int blocks = 2048;
    spmm_atomic_kernel<<<blocks, 256, 0, stream>>>(row, col, vals, embeds, out, n_edges);
}

// Round 2
// 617.848 us; speedup vs baseline: 4.2321x; 4.2321x over previous
//
#include <hip/hip_runtime.h>

#define D_FEAT 128

constexpr int SCAN_BLOCK = 256;
constexpr int SCAN_ITEMS = 8;
constexpr int SCAN_CHUNK = SCAN_BLOCK * SCAN_ITEMS; // 2048 elements per chunk

// ---------------- fallback (round-1) atomic kernel ----------------
__global__ void __launch_bounds__(256) spmm_atomic_kernel(
    const int* __restrict__ row, const int* __restrict__ col,
    const float* __restrict__ vals, const float* __restrict__ embeds,
    float* __restrict__ out, int n_edges)
{
    const int lane = threadIdx.x & 63;
    const int wave_in_block = threadIdx.x >> 6;
    const int waves_per_block = blockDim.x >> 6;
    const int n_waves = gridDim.x * waves_per_block;
    for (int e = blockIdx.x * waves_per_block + wave_in_block; e < n_edges; e += n_waves) {
        const int r = row[e];
        const int c = col[e];
        const float v = vals[e];
        const float2 emb = *reinterpret_cast<const float2*>(&embeds[(size_t)c * D_FEAT + lane * 2]);
        float* o = &out[(size_t)r * D_FEAT + lane * 2];
        atomicAdd(o, emb.x * v);
        atomicAdd(o + 1, emb.y * v);
    }
}

// ---------------- CSR build ----------------
__global__ void hist_kernel(const int* __restrict__ row, int* __restrict__ counts, int n)
{
    int i = blockIdx.x * blockDim.x + threadIdx.x;
    int stride = gridDim.x * blockDim.x;
    for (; i < n; i += stride) atomicAdd(&counts[row[i]], 1);
}

// Per-chunk exclusive scan; writes within-chunk exclusive prefix into scan_out,
// chunk totals into chunk_sums.
__global__ void __launch_bounds__(SCAN_BLOCK) scan1_kernel(
    const int* __restrict__ counts, int* __restrict__ scan_out,
    int* __restrict__ chunk_sums, int n)
{
    __shared__ int lds[SCAN_BLOCK];
    const int chunk = blockIdx.x;
    const int base = chunk * SCAN_CHUNK;
    const int tbase = base + threadIdx.x * SCAN_ITEMS;

    int pref[SCAN_ITEMS];
    int tsum = 0;
    for (int k = 0; k < SCAN_ITEMS; ++k) {
        int idx = tbase + k;
        int v = (idx < n) ? counts[idx] : 0;
        pref[k] = tsum;           // exclusive within thread
        tsum += v;
    }
    lds[threadIdx.x] = tsum;
    __syncthreads();
    // Hillis-Steele inclusive scan over per-thread sums
    for (int off = 1; off < SCAN_BLOCK; off <<= 1) {
        int v = (threadIdx.x >= off) ? lds[threadIdx.x - off] : 0;
        __syncthreads();
        lds[threadIdx.x] += v;
        __syncthreads();
    }
    const int texcl = (threadIdx.x == 0) ? 0 : lds[threadIdx.x - 1];
    for (int k = 0; k < SCAN_ITEMS; ++k) {
        int idx = tbase + k;
        if (idx < n) scan_out[idx] = texcl + pref[k];
    }
    if (threadIdx.x == SCAN_BLOCK - 1) chunk_sums[chunk] = lds[SCAN_BLOCK - 1];
}

__global__ void scan2_kernel(int* chunk_sums, int nchunks)
{
    if (blockIdx.x == 0 && threadIdx.x == 0) {
        int acc = 0;
        for (int i = 0; i < nchunks; ++i) { int v = chunk_sums[i]; chunk_sums[i] = acc; acc += v; }
    }
}

__global__ void scan3_kernel(int* __restrict__ row_ptr, const int* __restrict__ chunk_sums,
                             int n, int n_edges)
{
    int i = blockIdx.x * blockDim.x + threadIdx.x;
    if (i < n) row_ptr[i] += chunk_sums[i / SCAN_CHUNK];
    if (i == 0) row_ptr[n] = n_edges;
}

__global__ void scatter_kernel(const int* __restrict__ row, const int* __restrict__ col,
                               const float* __restrict__ vals,
                               const int* __restrict__ row_ptr, int* __restrict__ row_fill,
                               uint2* __restrict__ sorted_cv, int n_edges)
{
    int i = blockIdx.x * blockDim.x + threadIdx.x;
    int stride = gridDim.x * blockDim.x;
    for (; i < n_edges; i += stride) {
        int r = row[i];
        int pos = row_ptr[r] + atomicAdd(&row_fill[r], 1);
        uint2 cv;
        cv.x = (unsigned)col[i];
        cv.y = __float_as_uint(vals[i]);
        sorted_cv[pos] = cv;
    }
}

// ---------------- CSR SpMM: one wave per row, register accumulation ----------------
__global__ void __launch_bounds__(256) spmm_csr_kernel(
    const int* __restrict__ row_ptr, const uint2* __restrict__ sorted_cv,
    const float* __restrict__ embeds, float* __restrict__ out, int n_rows)
{
    const int lane = threadIdx.x & 63;
    const int wid = (blockIdx.x * blockDim.x + threadIdx.x) >> 6;
    const int n_waves = (gridDim.x * blockDim.x) >> 6;

    for (int r = wid; r < n_rows; r += n_waves) {
        const int start = row_ptr[r];
        const int end   = row_ptr[r + 1];
        float2 acc = {0.f, 0.f};

        int j = start;
        for (; j + 1 < end; j += 2) {
            uint2 cv0 = sorted_cv[j];
            uint2 cv1 = sorted_cv[j + 1];
            const float2 e0 = *reinterpret_cast<const float2*>(
                &embeds[(size_t)cv0.x * D_FEAT + lane * 2]);
            const float2 e1 = *reinterpret_cast<const float2*>(
                &embeds[(size_t)cv1.x * D_FEAT + lane * 2]);
            const float v0 = __uint_as_float(cv0.y);
            const float v1 = __uint_as_float(cv1.y);
            acc.x += v0 * e0.x + v1 * e1.x;
            acc.y += v0 * e0.y + v1 * e1.y;
        }
        if (j < end) {
            uint2 cv = sorted_cv[j];
            const float2 e = *reinterpret_cast<const float2*>(
                &embeds[(size_t)cv.x * D_FEAT + lane * 2]);
            const float v = __uint_as_float(cv.y);
            acc.x += v * e.x;
            acc.y += v * e.y;
        }
        *reinterpret_cast<float2*>(&out[(size_t)r * D_FEAT + lane * 2]) = acc;
    }
}

extern "C" void kernel_launch(void* const* d_in, const int* in_sizes, int n_in,
                              void* d_out, int out_size, void* d_ws, size_t ws_size,
                              hipStream_t stream) {
    const int*   row    = (const int*)d_in[0];
    const int*   col    = (const int*)d_in[1];
    const float* vals   = (const float*)d_in[2];
    const float* embeds = (const float*)d_in[3];
    float*       out    = (float*)d_out;

    const int n_edges = in_sizes[0];
    const int n_nodes = in_sizes[3] / D_FEAT;
    const int nchunks = (n_nodes + SCAN_CHUNK - 1) / SCAN_CHUNK;

    // workspace layout (8B-aligned first)
    size_t off = 0;
    uint2* sorted_cv = (uint2*)((char*)d_ws + off); off += (size_t)n_edges * 8;
    int* row_counts  = (int*)((char*)d_ws + off);   off += (size_t)n_nodes * 4;
    int* row_fill    = (int*)((char*)d_ws + off);   off += (size_t)n_nodes * 4;
    int* row_ptr     = (int*)((char*)d_ws + off);   off += (size_t)(n_nodes + 1) * 4;
    int* chunk_sums  = (int*)((char*)d_ws + off);   off += (size_t)nchunks * 4;

    if (off > ws_size) {
        // not enough scratch: fall back to proven atomic path
        hipMemsetAsync(d_out, 0, (size_t)out_size * sizeof(float), stream);
        spmm_atomic_kernel<<<2048, 256, 0, stream>>>(row, col, vals, embeds, out, n_edges);
        return;
    }

    // zero counts + fill (adjacent)
    hipMemsetAsync(row_counts, 0, (size_t)n_nodes * 2 * sizeof(int), stream);

    hist_kernel<<<2048, 256, 0, stream>>>(row, row_counts, n_edges);
    scan1_kernel<<<nchunks, SCAN_BLOCK, 0, stream>>>(row_counts, row_ptr, chunk_sums, n_nodes);
    scan2_kernel<<<1, 64, 0, stream>>>(chunk_sums, nchunks);
    scan3_kernel<<<(n_nodes + 256) / 256, 256, 0, stream>>>(row_ptr, chunk_sums, n_nodes, n_edges);
    scatter_kernel<<<2048, 256, 0, stream>>>(row, col, vals, row_ptr, row_fill, sorted_cv, n_edges);

    const int blocks = 4096; // 16384 waves, grid-stride over 100K rows
    spmm_csr_kernel<<<blocks, 256, 0, stream>>>(row_ptr, sorted_cv, embeds, out, n_nodes);
}

// Round 3
// 403.197 us; speedup vs baseline: 6.4852x; 1.5324x over previous
//
#include <hip/hip_runtime.h>

#define D_FEAT 128

constexpr int SCAN_BLOCK = 256;
constexpr int SCAN_ITEMS = 8;
constexpr int SCAN_CHUNK = SCAN_BLOCK * SCAN_ITEMS; // 2048 elements per chunk

constexpr int BUCKET_SHIFT = 8;      // 256 rows per bucket
constexpr int NB_MAX = 512;
constexpr int PART_TILE = 8192;      // edges per partition block

// ---------------- fallback (round-1) atomic kernel ----------------
__global__ void __launch_bounds__(256) spmm_atomic_kernel(
    const int* __restrict__ row, const int* __restrict__ col,
    const float* __restrict__ vals, const float* __restrict__ embeds,
    float* __restrict__ out, int n_edges)
{
    const int lane = threadIdx.x & 63;
    const int wave_in_block = threadIdx.x >> 6;
    const int waves_per_block = blockDim.x >> 6;
    const int n_waves = gridDim.x * waves_per_block;
    for (int e = blockIdx.x * waves_per_block + wave_in_block; e < n_edges; e += n_waves) {
        const int r = row[e];
        const int c = col[e];
        const float v = vals[e];
        const float2 emb = *reinterpret_cast<const float2*>(&embeds[(size_t)c * D_FEAT + lane * 2]);
        float* o = &out[(size_t)r * D_FEAT + lane * 2];
        atomicAdd(o, emb.x * v);
        atomicAdd(o + 1, emb.y * v);
    }
}

// ---------------- CSR build ----------------
__global__ void hist_kernel(const int* __restrict__ row, int* __restrict__ counts, int n)
{
    int i = blockIdx.x * blockDim.x + threadIdx.x;
    int stride = gridDim.x * blockDim.x;
    for (; i < n; i += stride) atomicAdd(&counts[row[i]], 1);
}

__global__ void __launch_bounds__(SCAN_BLOCK) scan1_kernel(
    const int* __restrict__ counts, int* __restrict__ scan_out,
    int* __restrict__ chunk_sums, int n)
{
    __shared__ int lds[SCAN_BLOCK];
    const int chunk = blockIdx.x;
    const int base = chunk * SCAN_CHUNK;
    const int tbase = base + threadIdx.x * SCAN_ITEMS;

    int pref[SCAN_ITEMS];
    int tsum = 0;
    for (int k = 0; k < SCAN_ITEMS; ++k) {
        int idx = tbase + k;
        int v = (idx < n) ? counts[idx] : 0;
        pref[k] = tsum;
        tsum += v;
    }
    lds[threadIdx.x] = tsum;
    __syncthreads();
    for (int off = 1; off < SCAN_BLOCK; off <<= 1) {
        int v = (threadIdx.x >= off) ? lds[threadIdx.x - off] : 0;
        __syncthreads();
        lds[threadIdx.x] += v;
        __syncthreads();
    }
    const int texcl = (threadIdx.x == 0) ? 0 : lds[threadIdx.x - 1];
    for (int k = 0; k < SCAN_ITEMS; ++k) {
        int idx = tbase + k;
        if (idx < n) scan_out[idx] = texcl + pref[k];
    }
    if (threadIdx.x == SCAN_BLOCK - 1) chunk_sums[chunk] = lds[SCAN_BLOCK - 1];
}

__global__ void scan2_kernel(int* chunk_sums, int nchunks)
{
    if (blockIdx.x == 0 && threadIdx.x == 0) {
        int acc = 0;
        for (int i = 0; i < nchunks; ++i) { int v = chunk_sums[i]; chunk_sums[i] = acc; acc += v; }
    }
}

__global__ void scan3_kernel(int* __restrict__ row_ptr, const int* __restrict__ chunk_sums,
                             int n, int n_edges)
{
    int i = blockIdx.x * blockDim.x + threadIdx.x;
    if (i < n) row_ptr[i] += chunk_sums[i / SCAN_CHUNK];
    if (i == 0) row_ptr[n] = n_edges;
}

// init bucket cursors to CSR base of each bucket
__global__ void bucket_init_kernel(const int* __restrict__ row_ptr, int* __restrict__ bucket_fill,
                                   int n_nodes, int nb)
{
    int b = blockIdx.x * blockDim.x + threadIdx.x;
    if (b <= nb) bucket_fill[b] = row_ptr[min(b << BUCKET_SHIFT, n_nodes)];
}

// pass 1: partition edges into 256-row buckets; payload packs (row_local, col) + val.
__global__ void __launch_bounds__(256) partition_kernel(
    const int* __restrict__ row, const int* __restrict__ col, const float* __restrict__ vals,
    int* __restrict__ bucket_fill, uint2* __restrict__ tmp, int n_edges, int nb)
{
    __shared__ int cnt[NB_MAX];
    __shared__ int start[NB_MAX];
    const int tid = threadIdx.x;
    const int base = blockIdx.x * PART_TILE;

    for (int b = tid; b < NB_MAX; b += 256) cnt[b] = 0;
    __syncthreads();

    for (int k = 0; k < PART_TILE / 256; ++k) {
        int e = base + k * 256 + tid;
        if (e < n_edges) atomicAdd(&cnt[row[e] >> BUCKET_SHIFT], 1);
    }
    __syncthreads();

    for (int b = tid; b < nb; b += 256) {
        int c = cnt[b];
        if (c > 0) start[b] = atomicAdd(&bucket_fill[b], c);
    }
    __syncthreads();

    for (int k = 0; k < PART_TILE / 256; ++k) {
        int e = base + k * 256 + tid;
        if (e < n_edges) {
            int r = row[e];
            int b = r >> BUCKET_SHIFT;
            int slot = atomicSub(&cnt[b], 1) - 1;   // local slot within this tile's chunk
            uint2 p;
            p.x = ((unsigned)(r & ((1 << BUCKET_SHIFT) - 1)) << 17) | (unsigned)col[e];
            p.y = __float_as_uint(vals[e]);
            tmp[start[b] + slot] = p;
        }
    }
}

// pass 2: within each bucket (writes confined to ~65KB window -> L2-local),
// place edges at exact CSR positions.
__global__ void __launch_bounds__(256) csr_scatter_kernel(
    const uint2* __restrict__ tmp, const int* __restrict__ row_ptr,
    int* __restrict__ row_fill, uint2* __restrict__ sorted_cv,
    int n_nodes, int blocks_per_bucket)
{
    const int b = blockIdx.x / blocks_per_bucket;
    const int sub = blockIdx.x % blocks_per_bucket;
    const int lo = row_ptr[min(b << BUCKET_SHIFT, n_nodes)];
    const int hi = row_ptr[min((b + 1) << BUCKET_SHIFT, n_nodes)];
    const int rbase = b << BUCKET_SHIFT;
    for (int e = lo + sub * 256 + threadIdx.x; e < hi; e += blocks_per_bucket * 256) {
        uint2 p = tmp[e];
        int r = rbase + (int)(p.x >> 17);
        int pos = row_ptr[r] + atomicAdd(&row_fill[r], 1);
        uint2 q;
        q.x = p.x & 0x1FFFFu;
        q.y = p.y;
        sorted_cv[pos] = q;
    }
}

// ---------------- embeds f32 -> bf16 ----------------
__device__ __forceinline__ unsigned short f2bf(float f)
{
    unsigned u = __float_as_uint(f);
    u += 0x7fffu + ((u >> 16) & 1);   // round-to-nearest-even
    return (unsigned short)(u >> 16);
}

__global__ void __launch_bounds__(256) convert_kernel(
    const float* __restrict__ embeds, unsigned short* __restrict__ out16, int n4)
{
    int i = blockIdx.x * blockDim.x + threadIdx.x;
    int stride = gridDim.x * blockDim.x;
    for (; i < n4; i += stride) {
        float4 f = *reinterpret_cast<const float4*>(&embeds[(size_t)i * 4]);
        ushort4 o;
        o.x = f2bf(f.x); o.y = f2bf(f.y); o.z = f2bf(f.z); o.w = f2bf(f.w);
        *reinterpret_cast<ushort4*>(&out16[(size_t)i * 4]) = o;
    }
}

// ---------------- CSR SpMM, bf16 gather, f32 accumulate ----------------
__global__ void __launch_bounds__(256) spmm_csr_bf16_kernel(
    const int* __restrict__ row_ptr, const uint2* __restrict__ sorted_cv,
    const unsigned short* __restrict__ embeds16, float* __restrict__ out, int n_rows)
{
    const int lane = threadIdx.x & 63;
    const int wid = (blockIdx.x * blockDim.x + threadIdx.x) >> 6;
    const int n_waves = (gridDim.x * blockDim.x) >> 6;

    for (int r = wid; r < n_rows; r += n_waves) {
        const int start = row_ptr[r];
        const int end   = row_ptr[r + 1];
        float ax = 0.f, ay = 0.f;

        int j = start;
        for (; j + 3 < end; j += 4) {
            uint2 cv0 = sorted_cv[j];
            uint2 cv1 = sorted_cv[j + 1];
            uint2 cv2 = sorted_cv[j + 2];
            uint2 cv3 = sorted_cv[j + 3];
            unsigned u0 = *reinterpret_cast<const unsigned*>(&embeds16[((size_t)cv0.x << 7) + lane * 2]);
            unsigned u1 = *reinterpret_cast<const unsigned*>(&embeds16[((size_t)cv1.x << 7) + lane * 2]);
            unsigned u2 = *reinterpret_cast<const unsigned*>(&embeds16[((size_t)cv2.x << 7) + lane * 2]);
            unsigned u3 = *reinterpret_cast<const unsigned*>(&embeds16[((size_t)cv3.x << 7) + lane * 2]);
            const float v0 = __uint_as_float(cv0.y);
            const float v1 = __uint_as_float(cv1.y);
            const float v2 = __uint_as_float(cv2.y);
            const float v3 = __uint_as_float(cv3.y);
            ax += v0 * __uint_as_float(u0 << 16) + v1 * __uint_as_float(u1 << 16)
                + v2 * __uint_as_float(u2 << 16) + v3 * __uint_as_float(u3 << 16);
            ay += v0 * __uint_as_float(u0 & 0xffff0000u) + v1 * __uint_as_float(u1 & 0xffff0000u)
                + v2 * __uint_as_float(u2 & 0xffff0000u) + v3 * __uint_as_float(u3 & 0xffff0000u);
        }
        for (; j < end; ++j) {
            uint2 cv = sorted_cv[j];
            unsigned u = *reinterpret_cast<const unsigned*>(&embeds16[((size_t)cv.x << 7) + lane * 2]);
            const float v = __uint_as_float(cv.y);
            ax += v * __uint_as_float(u << 16);
            ay += v * __uint_as_float(u & 0xffff0000u);
        }
        float2 res; res.x = ax; res.y = ay;
        *reinterpret_cast<float2*>(&out[(size_t)r * D_FEAT + lane * 2]) = res;
    }
}

// ---------------- round-2 f32 CSR SpMM (fallback) ----------------
__global__ void __launch_bounds__(256) spmm_csr_kernel(
    const int* __restrict__ row_ptr, const uint2* __restrict__ sorted_cv,
    const float* __restrict__ embeds, float* __restrict__ out, int n_rows)
{
    const int lane = threadIdx.x & 63;
    const int wid = (blockIdx.x * blockDim.x + threadIdx.x) >> 6;
    const int n_waves = (gridDim.x * blockDim.x) >> 6;

    for (int r = wid; r < n_rows; r += n_waves) {
        const int start = row_ptr[r];
        const int end   = row_ptr[r + 1];
        float2 acc = {0.f, 0.f};
        for (int j = start; j < end; ++j) {
            uint2 cv = sorted_cv[j];
            const float2 e = *reinterpret_cast<const float2*>(&embeds[(size_t)cv.x * D_FEAT + lane * 2]);
            const float v = __uint_as_float(cv.y);
            acc.x += v * e.x;
            acc.y += v * e.y;
        }
        *reinterpret_cast<float2*>(&out[(size_t)r * D_FEAT + lane * 2]) = acc;
    }
}

__global__ void scatter_kernel(const int* __restrict__ row, const int* __restrict__ col,
                               const float* __restrict__ vals,
                               const int* __restrict__ row_ptr, int* __restrict__ row_fill,
                               uint2* __restrict__ sorted_cv, int n_edges)
{
    int i = blockIdx.x * blockDim.x + threadIdx.x;
    int stride = gridDim.x * blockDim.x;
    for (; i < n_edges; i += stride) {
        int r = row[i];
        int pos = row_ptr[r] + atomicAdd(&row_fill[r], 1);
        uint2 cv;
        cv.x = (unsigned)col[i];
        cv.y = __float_as_uint(vals[i]);
        sorted_cv[pos] = cv;
    }
}

extern "C" void kernel_launch(void* const* d_in, const int* in_sizes, int n_in,
                              void* d_out, int out_size, void* d_ws, size_t ws_size,
                              hipStream_t stream) {
    const int*   row    = (const int*)d_in[0];
    const int*   col    = (const int*)d_in[1];
    const float* vals   = (const float*)d_in[2];
    const float* embeds = (const float*)d_in[3];
    float*       out    = (float*)d_out;

    const int n_edges = in_sizes[0];
    const int n_nodes = in_sizes[3] / D_FEAT;
    const int nchunks = (n_nodes + SCAN_CHUNK - 1) / SCAN_CHUNK;
    const int nb = (n_nodes + (1 << BUCKET_SHIFT) - 1) >> BUCKET_SHIFT;

    // workspace layout
    size_t bufA_bytes = (size_t)n_edges * 8;                       // tmp partition
    size_t bufA_alt   = (size_t)n_nodes * D_FEAT * 2;              // embeds bf16 (reuses bufA)
    if (bufA_alt > bufA_bytes) bufA_bytes = bufA_alt;
    bufA_bytes = (bufA_bytes + 255) & ~(size_t)255;

    size_t off = 0;
    char* base = (char*)d_ws;
    char*  bufA       = base + off;                 off += bufA_bytes;
    uint2* sorted_cv  = (uint2*)(base + off);       off += (size_t)n_edges * 8;
    int*   row_counts = (int*)(base + off);         off += (size_t)n_nodes * 4;
    int*   row_fill   = (int*)(base + off);         off += (size_t)n_nodes * 4;
    int*   row_ptr    = (int*)(base + off);         off += (size_t)(n_nodes + 1) * 4;
    int*   chunk_sums = (int*)(base + off);         off += (size_t)nchunks * 4;
    int*   bucket_fill= (int*)(base + off);         off += (size_t)(nb + 1) * 4;

    const bool full_path = (off <= ws_size) && (nb <= NB_MAX) && (n_nodes < (1 << 17));

    if (!full_path) {
        // round-2 fallback layout
        size_t off2 = 0;
        uint2* s_cv = (uint2*)(base + off2); off2 += (size_t)n_edges * 8;
        int* rc  = (int*)(base + off2); off2 += (size_t)n_nodes * 4;
        int* rf  = (int*)(base + off2); off2 += (size_t)n_nodes * 4;
        int* rp  = (int*)(base + off2); off2 += (size_t)(n_nodes + 1) * 4;
        int* cs  = (int*)(base + off2); off2 += (size_t)nchunks * 4;
        if (off2 > ws_size) {
            hipMemsetAsync(d_out, 0, (size_t)out_size * sizeof(float), stream);
            spmm_atomic_kernel<<<2048, 256, 0, stream>>>(row, col, vals, embeds, out, n_edges);
            return;
        }
        hipMemsetAsync(rc, 0, (size_t)n_nodes * 2 * sizeof(int), stream);
        hist_kernel<<<2048, 256, 0, stream>>>(row, rc, n_edges);
        scan1_kernel<<<nchunks, SCAN_BLOCK, 0, stream>>>(rc, rp, cs, n_nodes);
        scan2_kernel<<<1, 64, 0, stream>>>(cs, nchunks);
        scan3_kernel<<<(n_nodes + 256) / 256, 256, 0, stream>>>(rp, cs, n_nodes, n_edges);
        scatter_kernel<<<2048, 256, 0, stream>>>(row, col, vals, rp, rf, s_cv, n_edges);
        spmm_csr_kernel<<<4096, 256, 0, stream>>>(rp, s_cv, embeds, out, n_nodes);
        return;
    }

    uint2* tmp = (uint2*)bufA;
    unsigned short* embeds16 = (unsigned short*)bufA;   // reused AFTER pass2

    hipMemsetAsync(row_counts, 0, (size_t)n_nodes * 2 * sizeof(int), stream);

    hist_kernel<<<2048, 256, 0, stream>>>(row, row_counts, n_edges);
    scan1_kernel<<<nchunks, SCAN_BLOCK, 0, stream>>>(row_counts, row_ptr, chunk_sums, n_nodes);
    scan2_kernel<<<1, 64, 0, stream>>>(chunk_sums, nchunks);
    scan3_kernel<<<(n_nodes + 256) / 256, 256, 0, stream>>>(row_ptr, chunk_sums, n_nodes, n_edges);
    bucket_init_kernel<<<(nb + 256) / 256, 256, 0, stream>>>(row_ptr, bucket_fill, n_nodes, nb);

    const int part_blocks = (n_edges + PART_TILE - 1) / PART_TILE;
    partition_kernel<<<part_blocks, 256, 0, stream>>>(row, col, vals, bucket_fill, tmp, n_edges, nb);

    const int bpb = 8; // sub-blocks per bucket
    csr_scatter_kernel<<<nb * bpb, 256, 0, stream>>>(tmp, row_ptr, row_fill, sorted_cv,
                                                     n_nodes, bpb);

    const int n4 = n_nodes * D_FEAT / 4;
    convert_kernel<<<4096, 256, 0, stream>>>(embeds, embeds16, n4);

    spmm_csr_bf16_kernel<<<4096, 256, 0, stream>>>(row_ptr, sorted_cv, embeds16, out, n_nodes);
}

// Round 4
// 265.293 us; speedup vs baseline: 9.8564x; 1.5198x over previous
//
#include <hip/hip_runtime.h>

#define D_FEAT 128

constexpr int SCAN_BLOCK = 256;
constexpr int SCAN_ITEMS = 8;
constexpr int SCAN_CHUNK = SCAN_BLOCK * SCAN_ITEMS;

constexpr int BUCKET_SHIFT = 8;      // 256 rows per bucket
constexpr int NB_MAX = 512;
constexpr int PART_TILE = 8192;      // edges per partition block

// ---------------- fallback (round-1) atomic kernel ----------------
__global__ void __launch_bounds__(256) spmm_atomic_kernel(
    const int* __restrict__ row, const int* __restrict__ col,
    const float* __restrict__ vals, const float* __restrict__ embeds,
    float* __restrict__ out, int n_edges)
{
    const int lane = threadIdx.x & 63;
    const int wave_in_block = threadIdx.x >> 6;
    const int waves_per_block = blockDim.x >> 6;
    const int n_waves = gridDim.x * waves_per_block;
    for (int e = blockIdx.x * waves_per_block + wave_in_block; e < n_edges; e += n_waves) {
        const int r = row[e];
        const int c = col[e];
        const float v = vals[e];
        const float2 emb = *reinterpret_cast<const float2*>(&embeds[(size_t)c * D_FEAT + lane * 2]);
        float* o = &out[(size_t)r * D_FEAT + lane * 2];
        atomicAdd(o, emb.x * v);
        atomicAdd(o + 1, emb.y * v);
    }
}

// ================= fast path: bucket-granular CSR build =================

// LDS-privatized bucket histogram: no per-row atomics, one flush per block.
__global__ void __launch_bounds__(256) bucket_hist_kernel(
    const int* __restrict__ row, int* __restrict__ bucket_counts, int n_edges, int nb)
{
    __shared__ int cnt[NB_MAX];
    for (int b = threadIdx.x; b < nb; b += 256) cnt[b] = 0;
    __syncthreads();
    int i = blockIdx.x * blockDim.x + threadIdx.x;
    int stride = gridDim.x * blockDim.x;
    for (; i < n_edges; i += stride) atomicAdd(&cnt[row[i] >> BUCKET_SHIFT], 1);
    __syncthreads();
    for (int b = threadIdx.x; b < nb; b += 256) {
        int c = cnt[b];
        if (c) atomicAdd(&bucket_counts[b], c);
    }
}

// one block scans the bucket counts -> bucket_ptr (excl) + init bucket_fill
__global__ void __launch_bounds__(512) bucket_scan_kernel(
    const int* __restrict__ bucket_counts, int* __restrict__ bucket_ptr,
    int* __restrict__ bucket_fill, int* __restrict__ row_ptr,
    int nb, int n_nodes, int n_edges)
{
    __shared__ int lds[512];
    const int t = threadIdx.x;
    lds[t] = (t < nb) ? bucket_counts[t] : 0;
    __syncthreads();
    for (int off = 1; off < 512; off <<= 1) {
        int x = (t >= off) ? lds[t - off] : 0;
        __syncthreads();
        lds[t] += x;
        __syncthreads();
    }
    const int excl = (t == 0) ? 0 : lds[t - 1];
    if (t <= nb) bucket_ptr[t] = excl;
    if (t < nb)  bucket_fill[t] = excl;
    if (t == 0)  row_ptr[n_nodes] = n_edges;
}

// pass 1: partition edges into 256-row buckets; payload packs (row_local<<17 | col, val)
__global__ void __launch_bounds__(256) partition_kernel(
    const int* __restrict__ row, const int* __restrict__ col, const float* __restrict__ vals,
    int* __restrict__ bucket_fill, uint2* __restrict__ tmp, int n_edges, int nb)
{
    __shared__ int cnt[NB_MAX];
    __shared__ int start[NB_MAX];
    const int tid = threadIdx.x;
    const int base = blockIdx.x * PART_TILE;

    for (int b = tid; b < NB_MAX; b += 256) cnt[b] = 0;
    __syncthreads();

    for (int k = 0; k < PART_TILE / 256; ++k) {
        int e = base + k * 256 + tid;
        if (e < n_edges) atomicAdd(&cnt[row[e] >> BUCKET_SHIFT], 1);
    }
    __syncthreads();

    for (int b = tid; b < nb; b += 256) {
        int c = cnt[b];
        if (c > 0) start[b] = atomicAdd(&bucket_fill[b], c);
    }
    __syncthreads();

    for (int k = 0; k < PART_TILE / 256; ++k) {
        int e = base + k * 256 + tid;
        if (e < n_edges) {
            int r = row[e];
            int b = r >> BUCKET_SHIFT;
            int slot = atomicSub(&cnt[b], 1) - 1;
            uint2 p;
            p.x = ((unsigned)(r & ((1 << BUCKET_SHIFT) - 1)) << 17) | (unsigned)col[e];
            p.y = __float_as_uint(vals[e]);
            tmp[start[b] + slot] = p;
        }
    }
}

// pass 2 (fused hist+scan+scatter per bucket): LDS row counters + prefix scan,
// writes row_ptr and places edges at exact CSR slots. Zero global atomics.
__global__ void __launch_bounds__(256) bucket_finalize_kernel(
    const uint2* __restrict__ tmp, const int* __restrict__ bucket_ptr,
    int* __restrict__ row_ptr, uint2* __restrict__ sorted_cv, int n_nodes)
{
    __shared__ int cnt[256];
    __shared__ int excl[256];
    const int b = blockIdx.x;
    const int lo = bucket_ptr[b];
    const int hi = bucket_ptr[b + 1];
    const int t = threadIdx.x;

    cnt[t] = 0;
    __syncthreads();
    for (int e = lo + t; e < hi; e += 256)
        atomicAdd(&cnt[tmp[e].x >> 17], 1);
    __syncthreads();

    // inclusive scan of cnt into excl, then convert to exclusive
    excl[t] = cnt[t];
    __syncthreads();
    for (int off = 1; off < 256; off <<= 1) {
        int x = (t >= off) ? excl[t - off] : 0;
        __syncthreads();
        excl[t] += x;
        __syncthreads();
    }
    const int myexcl = excl[t] - cnt[t];   // own-index reads only
    const int r = (b << BUCKET_SHIFT) + t;
    if (r < n_nodes) row_ptr[r] = lo + myexcl;
    cnt[t] = 0;          // reuse as cursor
    excl[t] = myexcl;    // own-index write only
    __syncthreads();

    for (int e = lo + t; e < hi; e += 256) {
        uint2 p = tmp[e];
        int rl = p.x >> 17;
        int pos = lo + excl[rl] + atomicAdd(&cnt[rl], 1);
        uint2 q;
        q.x = p.x & 0x1FFFFu;
        q.y = p.y;
        sorted_cv[pos] = q;
    }
}

// ---------------- embeds f32 -> bf16 ----------------
__device__ __forceinline__ unsigned short f2bf(float f)
{
    unsigned u = __float_as_uint(f);
    u += 0x7fffu + ((u >> 16) & 1);   // round-to-nearest-even
    return (unsigned short)(u >> 16);
}

__global__ void __launch_bounds__(256) convert_kernel(
    const float* __restrict__ embeds, unsigned short* __restrict__ out16, int n4)
{
    int i = blockIdx.x * blockDim.x + threadIdx.x;
    int stride = gridDim.x * blockDim.x;
    for (; i < n4; i += stride) {
        float4 f = *reinterpret_cast<const float4*>(&embeds[(size_t)i * 4]);
        ushort4 o;
        o.x = f2bf(f.x); o.y = f2bf(f.y); o.z = f2bf(f.z); o.w = f2bf(f.w);
        *reinterpret_cast<ushort4*>(&out16[(size_t)i * 4]) = o;
    }
}

// ---------------- CSR SpMM, bf16 gather, f32 accumulate ----------------
__global__ void __launch_bounds__(256) spmm_csr_bf16_kernel(
    const int* __restrict__ row_ptr, const uint2* __restrict__ sorted_cv,
    const unsigned short* __restrict__ embeds16, float* __restrict__ out, int n_rows)
{
    const int lane = threadIdx.x & 63;
    const int wid = (blockIdx.x * blockDim.x + threadIdx.x) >> 6;
    const int n_waves = (gridDim.x * blockDim.x) >> 6;

    for (int r = wid; r < n_rows; r += n_waves) {
        const int start = row_ptr[r];
        const int end   = row_ptr[r + 1];
        float ax = 0.f, ay = 0.f;

        int j = start;
        for (; j + 3 < end; j += 4) {
            uint2 cv0 = sorted_cv[j];
            uint2 cv1 = sorted_cv[j + 1];
            uint2 cv2 = sorted_cv[j + 2];
            uint2 cv3 = sorted_cv[j + 3];
            unsigned u0 = *reinterpret_cast<const unsigned*>(&embeds16[((size_t)cv0.x << 7) + lane * 2]);
            unsigned u1 = *reinterpret_cast<const unsigned*>(&embeds16[((size_t)cv1.x << 7) + lane * 2]);
            unsigned u2 = *reinterpret_cast<const unsigned*>(&embeds16[((size_t)cv2.x << 7) + lane * 2]);
            unsigned u3 = *reinterpret_cast<const unsigned*>(&embeds16[((size_t)cv3.x << 7) + lane * 2]);
            const float v0 = __uint_as_float(cv0.y);
            const float v1 = __uint_as_float(cv1.y);
            const float v2 = __uint_as_float(cv2.y);
            const float v3 = __uint_as_float(cv3.y);
            ax += v0 * __uint_as_float(u0 << 16) + v1 * __uint_as_float(u1 << 16)
                + v2 * __uint_as_float(u2 << 16) + v3 * __uint_as_float(u3 << 16);
            ay += v0 * __uint_as_float(u0 & 0xffff0000u) + v1 * __uint_as_float(u1 & 0xffff0000u)
                + v2 * __uint_as_float(u2 & 0xffff0000u) + v3 * __uint_as_float(u3 & 0xffff0000u);
        }
        for (; j < end; ++j) {
            uint2 cv = sorted_cv[j];
            unsigned u = *reinterpret_cast<const unsigned*>(&embeds16[((size_t)cv.x << 7) + lane * 2]);
            const float v = __uint_as_float(cv.y);
            ax += v * __uint_as_float(u << 16);
            ay += v * __uint_as_float(u & 0xffff0000u);
        }
        float2 res; res.x = ax; res.y = ay;
        *reinterpret_cast<float2*>(&out[(size_t)r * D_FEAT + lane * 2]) = res;
    }
}

// ================= round-2 fallback pieces =================
__global__ void hist_kernel(const int* __restrict__ row, int* __restrict__ counts, int n)
{
    int i = blockIdx.x * blockDim.x + threadIdx.x;
    int stride = gridDim.x * blockDim.x;
    for (; i < n; i += stride) atomicAdd(&counts[row[i]], 1);
}

__global__ void __launch_bounds__(SCAN_BLOCK) scan1_kernel(
    const int* __restrict__ counts, int* __restrict__ scan_out,
    int* __restrict__ chunk_sums, int n)
{
    __shared__ int lds[SCAN_BLOCK];
    const int chunk = blockIdx.x;
    const int base = chunk * SCAN_CHUNK;
    const int tbase = base + threadIdx.x * SCAN_ITEMS;

    int pref[SCAN_ITEMS];
    int tsum = 0;
    for (int k = 0; k < SCAN_ITEMS; ++k) {
        int idx = tbase + k;
        int v = (idx < n) ? counts[idx] : 0;
        pref[k] = tsum;
        tsum += v;
    }
    lds[threadIdx.x] = tsum;
    __syncthreads();
    for (int off = 1; off < SCAN_BLOCK; off <<= 1) {
        int v = (threadIdx.x >= off) ? lds[threadIdx.x - off] : 0;
        __syncthreads();
        lds[threadIdx.x] += v;
        __syncthreads();
    }
    const int texcl = (threadIdx.x == 0) ? 0 : lds[threadIdx.x - 1];
    for (int k = 0; k < SCAN_ITEMS; ++k) {
        int idx = tbase + k;
        if (idx < n) scan_out[idx] = texcl + pref[k];
    }
    if (threadIdx.x == SCAN_BLOCK - 1) chunk_sums[chunk] = lds[SCAN_BLOCK - 1];
}

__global__ void scan2_kernel(int* chunk_sums, int nchunks)
{
    if (blockIdx.x == 0 && threadIdx.x == 0) {
        int acc = 0;
        for (int i = 0; i < nchunks; ++i) { int v = chunk_sums[i]; chunk_sums[i] = acc; acc += v; }
    }
}

__global__ void scan3_kernel(int* __restrict__ row_ptr, const int* __restrict__ chunk_sums,
                             int n, int n_edges)
{
    int i = blockIdx.x * blockDim.x + threadIdx.x;
    if (i < n) row_ptr[i] += chunk_sums[i / SCAN_CHUNK];
    if (i == 0) row_ptr[n] = n_edges;
}

__global__ void scatter_kernel(const int* __restrict__ row, const int* __restrict__ col,
                               const float* __restrict__ vals,
                               const int* __restrict__ row_ptr, int* __restrict__ row_fill,
                               uint2* __restrict__ sorted_cv, int n_edges)
{
    int i = blockIdx.x * blockDim.x + threadIdx.x;
    int stride = gridDim.x * blockDim.x;
    for (; i < n_edges; i += stride) {
        int r = row[i];
        int pos = row_ptr[r] + atomicAdd(&row_fill[r], 1);
        uint2 cv;
        cv.x = (unsigned)col[i];
        cv.y = __float_as_uint(vals[i]);
        sorted_cv[pos] = cv;
    }
}

__global__ void __launch_bounds__(256) spmm_csr_kernel(
    const int* __restrict__ row_ptr, const uint2* __restrict__ sorted_cv,
    const float* __restrict__ embeds, float* __restrict__ out, int n_rows)
{
    const int lane = threadIdx.x & 63;
    const int wid = (blockIdx.x * blockDim.x + threadIdx.x) >> 6;
    const int n_waves = (gridDim.x * blockDim.x) >> 6;

    for (int r = wid; r < n_rows; r += n_waves) {
        const int start = row_ptr[r];
        const int end   = row_ptr[r + 1];
        float2 acc = {0.f, 0.f};
        for (int j = start; j < end; ++j) {
            uint2 cv = sorted_cv[j];
            const float2 e = *reinterpret_cast<const float2*>(&embeds[(size_t)cv.x * D_FEAT + lane * 2]);
            const float v = __uint_as_float(cv.y);
            acc.x += v * e.x;
            acc.y += v * e.y;
        }
        *reinterpret_cast<float2*>(&out[(size_t)r * D_FEAT + lane * 2]) = acc;
    }
}

extern "C" void kernel_launch(void* const* d_in, const int* in_sizes, int n_in,
                              void* d_out, int out_size, void* d_ws, size_t ws_size,
                              hipStream_t stream) {
    const int*   row    = (const int*)d_in[0];
    const int*   col    = (const int*)d_in[1];
    const float* vals   = (const float*)d_in[2];
    const float* embeds = (const float*)d_in[3];
    float*       out    = (float*)d_out;

    const int n_edges = in_sizes[0];
    const int n_nodes = in_sizes[3] / D_FEAT;
    const int nchunks = (n_nodes + SCAN_CHUNK - 1) / SCAN_CHUNK;
    const int nb = (n_nodes + (1 << BUCKET_SHIFT) - 1) >> BUCKET_SHIFT;

    // workspace layout
    size_t bufA_bytes = (size_t)n_edges * 8;                 // tmp partition
    size_t bufA_alt   = (size_t)n_nodes * D_FEAT * 2;        // embeds bf16 (reuses bufA)
    if (bufA_alt > bufA_bytes) bufA_bytes = bufA_alt;
    bufA_bytes = (bufA_bytes + 255) & ~(size_t)255;

    size_t off = 0;
    char* base = (char*)d_ws;
    char*  bufA        = base + off;            off += bufA_bytes;
    uint2* sorted_cv   = (uint2*)(base + off);  off += (size_t)n_edges * 8;
    int*   row_ptr     = (int*)(base + off);    off += (size_t)(n_nodes + 1) * 4;
    int*   bucket_counts = (int*)(base + off);  off += (size_t)(nb + 1) * 4;
    int*   bucket_ptr  = (int*)(base + off);    off += (size_t)(nb + 1) * 4;
    int*   bucket_fill = (int*)(base + off);    off += (size_t)(nb + 1) * 4;

    const bool full_path = (off <= ws_size) && (nb <= 511) && (n_nodes <= (1 << 17));

    if (!full_path) {
        // round-2 fallback layout
        size_t off2 = 0;
        uint2* s_cv = (uint2*)(base + off2); off2 += (size_t)n_edges * 8;
        int* rc  = (int*)(base + off2); off2 += (size_t)n_nodes * 4;
        int* rf  = (int*)(base + off2); off2 += (size_t)n_nodes * 4;
        int* rp  = (int*)(base + off2); off2 += (size_t)(n_nodes + 1) * 4;
        int* cs  = (int*)(base + off2); off2 += (size_t)nchunks * 4;
        if (off2 > ws_size) {
            hipMemsetAsync(d_out, 0, (size_t)out_size * sizeof(float), stream);
            spmm_atomic_kernel<<<2048, 256, 0, stream>>>(row, col, vals, embeds, out, n_edges);
            return;
        }
        hipMemsetAsync(rc, 0, (size_t)n_nodes * 2 * sizeof(int), stream);
        hist_kernel<<<2048, 256, 0, stream>>>(row, rc, n_edges);
        scan1_kernel<<<nchunks, SCAN_BLOCK, 0, stream>>>(rc, rp, cs, n_nodes);
        scan2_kernel<<<1, 64, 0, stream>>>(cs, nchunks);
        scan3_kernel<<<(n_nodes + 256) / 256, 256, 0, stream>>>(rp, cs, n_nodes, n_edges);
        scatter_kernel<<<2048, 256, 0, stream>>>(row, col, vals, rp, rf, s_cv, n_edges);
        spmm_csr_kernel<<<4096, 256, 0, stream>>>(rp, s_cv, embeds, out, n_nodes);
        return;
    }

    uint2* tmp = (uint2*)bufA;
    unsigned short* embeds16 = (unsigned short*)bufA;   // reused AFTER finalize reads tmp

    hipMemsetAsync(bucket_counts, 0, (size_t)(nb + 1) * sizeof(int), stream);

    bucket_hist_kernel<<<1024, 256, 0, stream>>>(row, bucket_counts, n_edges, nb);
    bucket_scan_kernel<<<1, 512, 0, stream>>>(bucket_counts, bucket_ptr, bucket_fill,
                                              row_ptr, nb, n_nodes, n_edges);

    const int part_blocks = (n_edges + PART_TILE - 1) / PART_TILE;
    partition_kernel<<<part_blocks, 256, 0, stream>>>(row, col, vals, bucket_fill, tmp, n_edges, nb);

    bucket_finalize_kernel<<<nb, 256, 0, stream>>>(tmp, bucket_ptr, row_ptr, sorted_cv, n_nodes);

    const int n4 = n_nodes * D_FEAT / 4;
    convert_kernel<<<4096, 256, 0, stream>>>(embeds, embeds16, n4);

    spmm_csr_bf16_kernel<<<4096, 256, 0, stream>>>(row_ptr, sorted_cv, embeds16, out, n_nodes);
}